// Round 1
// baseline (637.202 us; speedup 1.0000x reference)
//
#include <hip/hip_runtime.h>
#include <math.h>

#define NB   4      // batch
#define CIN  128
#define C    64
#define HH   64
#define WW   64
#define HW   4096
#define C8   8
#define RR   4
#define TWOC 128
#define TN   32     // attention rows per block
#define TM   128    // attention m-tile

// ---------------- conv1x1 (per-batch GEMM over channels) ----------------
__global__ void conv1x1_kernel(const float* __restrict__ x, const float* __restrict__ w,
                               const float* __restrict__ bias, float* __restrict__ y,
                               int Cin_, int Cout_) {
    int idx = blockIdx.x * 256 + threadIdx.x;          // over NB*Cout*HW
    int hw = idx & (HW - 1);
    int t  = idx >> 12;
    int o  = t % Cout_;
    int b  = t / Cout_;
    const float* xp = x + (size_t)(b * Cin_) * HW + hw;
    const float* wp = w + o * Cin_;
    float acc = bias ? bias[o] : 0.f;
    for (int c = 0; c < Cin_; ++c) acc += xp[(size_t)c * HW] * wp[c];
    y[idx] = acc;
}

// ---------------- mean over HW per (b,c) ----------------
__global__ void mean_hw_kernel(const float* __restrict__ x, float* __restrict__ out) {
    int bc = blockIdx.x, tid = threadIdx.x;
    float s = 0.f;
    for (int i = tid; i < HW; i += 256) s += x[(size_t)bc * HW + i];
    for (int d = 32; d > 0; d >>= 1) s += __shfl_down(s, d);
    __shared__ float rs[4];
    if ((tid & 63) == 0) rs[tid >> 6] = s;
    __syncthreads();
    if (tid == 0) out[bc] = (rs[0] + rs[1] + rs[2] + rs[3]) * (1.f / HW);
}

// ---------------- channel attention MLP: sigmoid(w2 @ relu(w1 @ avg)) ----------------
__global__ void ca_kernel(const float* __restrict__ avg, const float* __restrict__ w1,
                          const float* __restrict__ w2, float* __restrict__ out) {
    int tid = threadIdx.x;           // 256 = NB*C
    int b = tid >> 6, c = tid & 63;
    __shared__ float h[NB][RR];
    if (tid < NB * RR) {
        int hb = tid >> 2, hr = tid & 3;
        float a = 0.f;
        for (int cc = 0; cc < C; ++cc) a += avg[hb * C + cc] * w1[hr * C + cc];
        h[hb][hr] = fmaxf(a, 0.f);
    }
    __syncthreads();
    float a = 0.f;
    for (int r = 0; r < RR; ++r) a += h[b][r] * w2[c * RR + r];
    out[b * C + c] = 1.f / (1.f + __expf(-a));
}

// ---------------- channel avg/max pooling -> [B,HW] each ----------------
__global__ void chan_pool_kernel(const float* __restrict__ x,
                                 float* __restrict__ avgo, float* __restrict__ maxo) {
    int idx = blockIdx.x * 256 + threadIdx.x;  // NB*HW
    int b = idx >> 12, hw = idx & 4095;
    const float* xp = x + (size_t)(b * C) * HW + hw;
    float s = 0.f, m = -1e30f;
    for (int c = 0; c < C; ++c) { float v = xp[(size_t)c * HW]; s += v; m = fmaxf(m, v); }
    avgo[idx] = s * (1.f / C);
    maxo[idx] = m;
}

// ---------------- spatial attention 7x7 conv + sigmoid ----------------
__global__ void sa_conv_kernel(const float* __restrict__ avgc, const float* __restrict__ maxc,
                               const float* __restrict__ w, const float* __restrict__ bsa,
                               float* __restrict__ out) {
    __shared__ float wsh[98];
    if (threadIdx.x < 98) wsh[threadIdx.x] = w[threadIdx.x];
    __syncthreads();
    int idx = blockIdx.x * 256 + threadIdx.x;  // NB*HW
    int b = idx >> 12, hw = idx & 4095;
    int y0 = hw >> 6, x0 = hw & 63;
    float acc = bsa[0];
    for (int dy = -3; dy <= 3; ++dy) {
        int yy = y0 + dy; if (yy < 0 || yy >= HH) continue;
        for (int dx = -3; dx <= 3; ++dx) {
            int xx = x0 + dx; if (xx < 0 || xx >= WW) continue;
            int widx = (dy + 3) * 7 + (dx + 3);
            int p = b * HW + yy * WW + xx;
            acc += avgc[p] * wsh[widx] + maxc[p] * wsh[49 + widx];
        }
    }
    out[idx] = 1.f / (1.f + __expf(-acc));
}

// ---------------- apply channel & spatial gates in place ----------------
__global__ void apply_attn_kernel(float* __restrict__ x, const float* __restrict__ ca,
                                  const float* __restrict__ sa) {
    int idx = blockIdx.x * 256 + threadIdx.x;  // NB*C*HW
    int hw = idx & 4095;
    int bc = idx >> 12;
    int b  = bc >> 6;
    x[idx] = x[idx] * ca[bc] * sa[b * HW + hw];
}

// ---------------- flash-style cross attention ----------------
__global__ __launch_bounds__(256) void cross_attn_kernel(
    const float* __restrict__ q, const float* __restrict__ k, const float* __restrict__ v,
    const float* __restrict__ es, const float* __restrict__ gammap, float* __restrict__ out) {
    const int b  = blockIdx.x >> 7;            // HW/TN = 128 tiles per batch
    const int n0 = (blockIdx.x & 127) * TN;
    const int tid = threadIdx.x;
    const int row = tid >> 3;                  // 0..31
    const int cg  = tid & 7;                   // c group

    __shared__ float qs[C8][TN];
    __shared__ float ks[C8][TM];
    __shared__ float vs[C][TM + 4];
    __shared__ float ps[TN][TM + 4];
    __shared__ float mi[TN], li[TN];

    { int c8 = tid >> 5, j = tid & 31;
      qs[c8][j] = q[(size_t)(b * C8 + c8) * HW + n0 + j]; }
    if (tid < TN) { mi[tid] = -1e30f; li[tid] = 0.f; }
    float acc[8];
    #pragma unroll
    for (int i = 0; i < 8; ++i) acc[i] = 0.f;
    __syncthreads();

    for (int m0 = 0; m0 < HW; m0 += TM) {
        for (int i = tid; i < C8 * TM; i += 256) {
            int c8 = i >> 7, j = i & 127;
            ks[c8][j] = k[(size_t)(b * C8 + c8) * HW + m0 + j];
        }
        for (int i = tid; i < C * TM; i += 256) {
            int c = i >> 7, j = i & 127;
            vs[c][j] = v[(size_t)(b * C + c) * HW + m0 + j];
        }
        __syncthreads();

        float qr[C8];
        #pragma unroll
        for (int c8 = 0; c8 < C8; ++c8) qr[c8] = qs[c8][row];

        float lv[16]; float lmax = -1e30f;
        #pragma unroll
        for (int jj = 0; jj < 16; ++jj) {
            int j = cg + (jj << 3);
            float a = 0.f;
            #pragma unroll
            for (int c8 = 0; c8 < C8; ++c8) a += qr[c8] * ks[c8][j];
            lv[jj] = a; lmax = fmaxf(lmax, a);
        }
        #pragma unroll
        for (int d = 1; d < 8; d <<= 1) lmax = fmaxf(lmax, __shfl_xor(lmax, d));

        float mold = mi[row];
        float mnew = fmaxf(mold, lmax);
        float corr = __expf(mold - mnew);
        float rsum = 0.f;
        #pragma unroll
        for (int jj = 0; jj < 16; ++jj) {
            float p = __expf(lv[jj] - mnew);
            ps[row][cg + (jj << 3)] = p;
            rsum += p;
        }
        #pragma unroll
        for (int d = 1; d < 8; d <<= 1) rsum += __shfl_xor(rsum, d);
        if (cg == 0) { mi[row] = mnew; li[row] = li[row] * corr + rsum; }
        #pragma unroll
        for (int i = 0; i < 8; ++i) acc[i] *= corr;
        __syncthreads();

        // PV: acc[ii] += sum_j p[row][j] * v[cg+8*ii][j]
        for (int j = 0; j < TM; j += 4) {
            const float4 p4 = *(const float4*)&ps[row][j];
            #pragma unroll
            for (int ii = 0; ii < 8; ++ii) {
                const float4 v4 = *(const float4*)&vs[cg + (ii << 3)][j];
                acc[ii] += p4.x * v4.x + p4.y * v4.y + p4.z * v4.z + p4.w * v4.w;
            }
        }
        __syncthreads();
    }

    float g = gammap[0];
    float linv = 1.f / li[row];
    int n = n0 + row;
    #pragma unroll
    for (int ii = 0; ii < 8; ++ii) {
        int c = cg + (ii << 3);
        size_t idx = (size_t)(b * C + c) * HW + n;
        out[idx] = g * acc[ii] * linv + es[idx];
    }
}

// ---------------- refine conv1x1 over concat [cross, es] ----------------
__global__ void refine_kernel(const float* __restrict__ cross, const float* __restrict__ es,
                              const float* __restrict__ rw, const float* __restrict__ rb,
                              float* __restrict__ y) {
    int idx = blockIdx.x * 256 + threadIdx.x;  // NB*TWOC*HW
    int hw = idx & 4095;
    int t  = idx >> 12;
    int o  = t & 127;
    int b  = t >> 7;
    const float* c1 = cross + (size_t)(b * C) * HW + hw;
    const float* c2 = es    + (size_t)(b * C) * HW + hw;
    const float* w  = rw + o * TWOC;
    float acc = rb[o];
    for (int c = 0; c < C; ++c) acc += c1[(size_t)c * HW] * w[c];
    for (int c = 0; c < C; ++c) acc += c2[(size_t)c * HW] * w[C + c];
    y[idx] = acc;
}

// ---------------- BN stats per channel ----------------
__global__ void bn_stats_kernel(const float* __restrict__ y,
                                float* __restrict__ meanv, float* __restrict__ varv) {
    int o = blockIdx.x, tid = threadIdx.x;
    float s = 0.f, s2 = 0.f;
    for (int i = tid; i < NB * HW; i += 256) {
        int b = i >> 12, hw = i & 4095;
        float val = y[(size_t)(b * TWOC + o) * HW + hw];
        s += val; s2 += val * val;
    }
    for (int d = 32; d > 0; d >>= 1) { s += __shfl_down(s, d); s2 += __shfl_down(s2, d); }
    __shared__ float rs[4], rs2[4];
    if ((tid & 63) == 0) { rs[tid >> 6] = s; rs2[tid >> 6] = s2; }
    __syncthreads();
    if (tid == 0) {
        float S = rs[0] + rs[1] + rs[2] + rs[3];
        float S2 = rs2[0] + rs2[1] + rs2[2] + rs2[3];
        float m = S * (1.f / (NB * HW));
        meanv[o] = m;
        varv[o]  = S2 * (1.f / (NB * HW)) - m * m;
    }
}

// ---------------- BN apply + relu (in place on d_out) ----------------
__global__ void bn_apply_kernel(float* __restrict__ y, const float* __restrict__ meanv,
                                const float* __restrict__ varv, const float* __restrict__ sc,
                                const float* __restrict__ bi) {
    int idx = blockIdx.x * 256 + threadIdx.x;  // NB*TWOC*HW
    int o = (idx >> 12) & 127;
    float xn = (y[idx] - meanv[o]) * rsqrtf(varv[o] + 1e-5f);
    y[idx] = fmaxf(xn * sc[o] + bi[o], 0.f);
}

extern "C" void kernel_launch(void* const* d_in, const int* in_sizes, int n_in,
                              void* d_out, int out_size, void* d_ws, size_t ws_size,
                              hipStream_t stream) {
    const float* swin   = (const float*)d_in[0];
    const float* resnet = (const float*)d_in[1];
    const float* proj_w = (const float*)d_in[2];
    const float* proj_b = (const float*)d_in[3];
    const float* ca_w1  = (const float*)d_in[4];
    const float* ca_w2  = (const float*)d_in[5];
    const float* sa_w   = (const float*)d_in[6];
    const float* sa_b   = (const float*)d_in[7];
    const float* q_w    = (const float*)d_in[8];
    const float* q_b    = (const float*)d_in[9];
    const float* k_w    = (const float*)d_in[10];
    const float* k_b    = (const float*)d_in[11];
    const float* v_w    = (const float*)d_in[12];
    const float* v_b    = (const float*)d_in[13];
    const float* gamma  = (const float*)d_in[14];
    const float* ref_w  = (const float*)d_in[15];
    const float* ref_b  = (const float*)d_in[16];
    const float* bn_sc  = (const float*)d_in[17];
    const float* bn_bi  = (const float*)d_in[18];
    float* out = (float*)d_out;

    float* ws = (float*)d_ws;
    // workspace layout (floats)
    float* s      = ws;                 // 1048576
    float* r      = s + 1048576;        // 1048576
    float* cross  = r + 1048576;        // 1048576
    float* vbuf   = cross + 1048576;    // 1048576
    float* qbuf   = vbuf + 1048576;     // 131072
    float* kbuf   = qbuf + 131072;      // 131072
    float* avg_s  = kbuf + 131072;      // 256
    float* avg_r  = avg_s + 256;        // 256
    float* ca_s   = avg_r + 256;        // 256
    float* ca_r   = ca_s + 256;         // 256
    float* avgc_s = ca_r + 256;         // 16384
    float* maxc_s = avgc_s + 16384;     // 16384
    float* avgc_r = maxc_s + 16384;     // 16384
    float* maxc_r = avgc_r + 16384;     // 16384
    float* sa_s   = maxc_r + 16384;     // 16384
    float* sa_r   = sa_s + 16384;       // 16384
    float* bn_m   = sa_r + 16384;       // 128
    float* bn_v   = bn_m + 128;         // 128

    // 1. projections
    conv1x1_kernel<<<NB * C * HW / 256, 256, 0, stream>>>(swin, proj_w, proj_b, s, CIN, C);
    conv1x1_kernel<<<NB * C * HW / 256, 256, 0, stream>>>(resnet, proj_w, proj_b, r, CIN, C);
    // 2. channel attention
    mean_hw_kernel<<<NB * C, 256, 0, stream>>>(s, avg_s);
    mean_hw_kernel<<<NB * C, 256, 0, stream>>>(r, avg_r);
    ca_kernel<<<1, 256, 0, stream>>>(avg_s, ca_w1, ca_w2, ca_s);
    ca_kernel<<<1, 256, 0, stream>>>(avg_r, ca_w1, ca_w2, ca_r);
    // 3. spatial attention
    chan_pool_kernel<<<NB * HW / 256, 256, 0, stream>>>(s, avgc_s, maxc_s);
    chan_pool_kernel<<<NB * HW / 256, 256, 0, stream>>>(r, avgc_r, maxc_r);
    sa_conv_kernel<<<NB * HW / 256, 256, 0, stream>>>(avgc_s, maxc_s, sa_w, sa_b, sa_s);
    sa_conv_kernel<<<NB * HW / 256, 256, 0, stream>>>(avgc_r, maxc_r, sa_w, sa_b, sa_r);
    // 4. apply gates (s -> es, r -> er, in place)
    apply_attn_kernel<<<NB * C * HW / 256, 256, 0, stream>>>(s, ca_s, sa_s);
    apply_attn_kernel<<<NB * C * HW / 256, 256, 0, stream>>>(r, ca_r, sa_r);
    // 5. q, k, v projections
    conv1x1_kernel<<<NB * C8 * HW / 256, 256, 0, stream>>>(s, q_w, q_b, qbuf, C, C8);
    conv1x1_kernel<<<NB * C8 * HW / 256, 256, 0, stream>>>(r, k_w, k_b, kbuf, C, C8);
    conv1x1_kernel<<<NB * C * HW / 256, 256, 0, stream>>>(r, v_w, v_b, vbuf, C, C);
    // 6. cross attention (flash-style), writes cross = gamma*attn_out + es
    cross_attn_kernel<<<NB * (HW / TN), 256, 0, stream>>>(qbuf, kbuf, vbuf, s, gamma, cross);
    // 7. refine over concat [cross, es] -> d_out (used as y scratch)
    refine_kernel<<<NB * TWOC * HW / 256, 256, 0, stream>>>(cross, s, ref_w, ref_b, out);
    // 8. BN stats + apply + relu
    bn_stats_kernel<<<TWOC, 256, 0, stream>>>(out, bn_m, bn_v);
    bn_apply_kernel<<<NB * TWOC * HW / 256, 256, 0, stream>>>(out, bn_m, bn_v, bn_sc, bn_bi);
}

// Round 2
// 411.858 us; speedup vs baseline: 1.5471x; 1.5471x over previous
//
#include <hip/hip_runtime.h>
#include <hip/hip_bf16.h>
#include <math.h>

#define NB   4      // batch
#define CIN  128
#define C    64
#define HH   64
#define WW   64
#define HW   4096
#define C8   8
#define RR   4
#define TWOC 128

typedef __attribute__((ext_vector_type(8))) short short8;
typedef __attribute__((ext_vector_type(4))) float f32x4;
typedef __attribute__((ext_vector_type(4))) int int4v;

__device__ inline ushort f2bf(float f) {
    union { float f; unsigned u; } x{ f };
    unsigned r = x.u + 0x7FFFu + ((x.u >> 16) & 1u);   // RNE
    return (ushort)(r >> 16);
}

// ---------------- conv1x1 (per-batch GEMM over channels), fp32 ----------------
__global__ void conv1x1_kernel(const float* __restrict__ x, const float* __restrict__ w,
                               const float* __restrict__ bias, float* __restrict__ y,
                               int Cin_, int Cout_) {
    int idx = blockIdx.x * 256 + threadIdx.x;          // over NB*Cout*HW
    int hw = idx & (HW - 1);
    int t  = idx >> 12;
    int o  = t % Cout_;
    int b  = t / Cout_;
    const float* xp = x + (size_t)(b * Cin_) * HW + hw;
    const float* wp = w + o * Cin_;
    float acc = bias ? bias[o] : 0.f;
    for (int c = 0; c < Cin_; ++c) acc += xp[(size_t)c * HW] * wp[c];
    y[idx] = acc;
}

// ---------------- mean over HW per (b,c) ----------------
__global__ void mean_hw_kernel(const float* __restrict__ x, float* __restrict__ out) {
    int bc = blockIdx.x, tid = threadIdx.x;
    float s = 0.f;
    for (int i = tid; i < HW; i += 256) s += x[(size_t)bc * HW + i];
    for (int d = 32; d > 0; d >>= 1) s += __shfl_down(s, d);
    __shared__ float rs[4];
    if ((tid & 63) == 0) rs[tid >> 6] = s;
    __syncthreads();
    if (tid == 0) out[bc] = (rs[0] + rs[1] + rs[2] + rs[3]) * (1.f / HW);
}

// ---------------- channel attention MLP ----------------
__global__ void ca_kernel(const float* __restrict__ avg, const float* __restrict__ w1,
                          const float* __restrict__ w2, float* __restrict__ out) {
    int tid = threadIdx.x;           // 256 = NB*C
    int b = tid >> 6, c = tid & 63;
    __shared__ float h[NB][RR];
    if (tid < NB * RR) {
        int hb = tid >> 2, hr = tid & 3;
        float a = 0.f;
        for (int cc = 0; cc < C; ++cc) a += avg[hb * C + cc] * w1[hr * C + cc];
        h[hb][hr] = fmaxf(a, 0.f);
    }
    __syncthreads();
    float a = 0.f;
    for (int r = 0; r < RR; ++r) a += h[b][r] * w2[c * RR + r];
    out[b * C + c] = 1.f / (1.f + __expf(-a));
}

// ---------------- channel avg/max pooling ----------------
__global__ void chan_pool_kernel(const float* __restrict__ x,
                                 float* __restrict__ avgo, float* __restrict__ maxo) {
    int idx = blockIdx.x * 256 + threadIdx.x;  // NB*HW
    int b = idx >> 12, hw = idx & 4095;
    const float* xp = x + (size_t)(b * C) * HW + hw;
    float s = 0.f, m = -1e30f;
    for (int c = 0; c < C; ++c) { float v = xp[(size_t)c * HW]; s += v; m = fmaxf(m, v); }
    avgo[idx] = s * (1.f / C);
    maxo[idx] = m;
}

// ---------------- spatial attention 7x7 conv + sigmoid ----------------
__global__ void sa_conv_kernel(const float* __restrict__ avgc, const float* __restrict__ maxc,
                               const float* __restrict__ w, const float* __restrict__ bsa,
                               float* __restrict__ out) {
    __shared__ float wsh[98];
    if (threadIdx.x < 98) wsh[threadIdx.x] = w[threadIdx.x];
    __syncthreads();
    int idx = blockIdx.x * 256 + threadIdx.x;  // NB*HW
    int b = idx >> 12, hw = idx & 4095;
    int y0 = hw >> 6, x0 = hw & 63;
    float acc = bsa[0];
    for (int dy = -3; dy <= 3; ++dy) {
        int yy = y0 + dy; if (yy < 0 || yy >= HH) continue;
        for (int dx = -3; dx <= 3; ++dx) {
            int xx = x0 + dx; if (xx < 0 || xx >= WW) continue;
            int widx = (dy + 3) * 7 + (dx + 3);
            int p = b * HW + yy * WW + xx;
            acc += avgc[p] * wsh[widx] + maxc[p] * wsh[49 + widx];
        }
    }
    out[idx] = 1.f / (1.f + __expf(-acc));
}

// ---------------- apply channel & spatial gates in place ----------------
__global__ void apply_attn_kernel(float* __restrict__ x, const float* __restrict__ ca,
                                  const float* __restrict__ sa) {
    int idx = blockIdx.x * 256 + threadIdx.x;  // NB*C*HW
    int hw = idx & 4095;
    int bc = idx >> 12;
    int b  = bc >> 6;
    x[idx] = x[idx] * ca[bc] * sa[b * HW + hw];
}

// ---------------- fused q/k projections -> bf16 [b][hw][8] ----------------
__global__ void qk_proj_kernel(const float* __restrict__ es, const float* __restrict__ er,
                               const float* __restrict__ qw, const float* __restrict__ qbv,
                               const float* __restrict__ kw, const float* __restrict__ kbv,
                               ushort* __restrict__ q_t, ushort* __restrict__ k_t) {
    int idx = blockIdx.x * 256 + threadIdx.x;   // NB*HW
    int b = idx >> 12, hw = idx & 4095;
    float qa[C8], ka[C8];
    #pragma unroll
    for (int o = 0; o < C8; ++o) { qa[o] = qbv[o]; ka[o] = kbv[o]; }
    const float* esp = es + (size_t)(b * C) * HW + hw;
    const float* erp = er + (size_t)(b * C) * HW + hw;
    for (int c = 0; c < C; ++c) {
        float xs = esp[(size_t)c * HW];
        float xr = erp[(size_t)c * HW];
        #pragma unroll
        for (int o = 0; o < C8; ++o) { qa[o] += xs * qw[o * C + c]; ka[o] += xr * kw[o * C + c]; }
    }
    union { ushort u[8]; int4v v; } qo, ko;
    #pragma unroll
    for (int o = 0; o < C8; ++o) { qo.u[o] = f2bf(qa[o]); ko.u[o] = f2bf(ka[o]); }
    *(int4v*)(q_t + (size_t)idx * 8) = qo.v;
    *(int4v*)(k_t + (size_t)idx * 8) = ko.v;
}

// ---------------- v projection -> bf16 [b][c][hw] ----------------
__global__ void v_proj_kernel(const float* __restrict__ er, const float* __restrict__ vw,
                              const float* __restrict__ vbv, ushort* __restrict__ v_t) {
    int idx = blockIdx.x * 256 + threadIdx.x;   // NB*C*HW
    int hw = idx & 4095;
    int bc = idx >> 12;
    int c = bc & 63, b = bc >> 6;
    const float* erp = er + (size_t)(b * C) * HW + hw;
    float acc = vbv[c];
    for (int cc = 0; cc < C; ++cc) acc += erp[(size_t)cc * HW] * vw[c * C + cc];
    v_t[idx] = f2bf(acc);
}

// ---------------- MFMA flash cross-attention ----------------
// One wave owns out[64c x 16n] for one batch. S' = mfma(K^T, Q) (swapped) so
// softmax is lane-local per column n. P->B-frag via cvt_pk_bf16 + ds_bpermute.
__global__ __launch_bounds__(256) void cross_attn_mfma(
    const ushort* __restrict__ q_t, const ushort* __restrict__ k_t,
    const ushort* __restrict__ v_t, const float* __restrict__ es,
    const float* __restrict__ gammap, float* __restrict__ out)
{
    const int tid  = threadIdx.x;
    const int wave = (blockIdx.x << 2) + (tid >> 6);   // 0..1023
    const int lane = tid & 63;
    const int b    = wave >> 8;
    const int n0   = (wave & 255) << 4;
    const int g    = lane >> 4;
    const int colL = lane & 15;
    const int hsel = g >> 1;
    const int addrA = (((g & 1) << 5) + colL) << 2;    // src lane*4 for b-frag dw 0,1
    const int addrB = addrA + 64;                      // +16 lanes for dw 2,3

    // Q b-frag: lanes<16 hold Q[c8=0..7][n0+lane]; zero-pad k>=8
    short8 qf = short8(0);
    if (lane < 16) qf = *(const short8*)(q_t + ((size_t)(b * HW) + n0 + lane) * 8);

    f32x4 acc0 = {0.f,0.f,0.f,0.f}, acc1 = acc0, acc2 = acc0, acc3 = acc0;
    const f32x4 zf = {0.f,0.f,0.f,0.f};
    float mrun = -1e30f, lrun = 0.f;

    const ushort* kbase = k_t + (size_t)(b * HW) * 8;
    const ushort* vbase = v_t + (size_t)(b * C) * HW + colL * (size_t)HW + (g << 3);

    for (int m0 = 0; m0 < HW; m0 += 32) {
        // K a-frags (two 16-row m-halves), lanes<16 only, zero-pad k>=8
        short8 kf0 = short8(0), kf1 = short8(0);
        if (lane < 16) {
            kf0 = *(const short8*)(kbase + ((size_t)(m0 + lane)) * 8);
            kf1 = *(const short8*)(kbase + ((size_t)(m0 + 16 + lane)) * 8);
        }
        // V a-frags: A[c-local][m-local], 4 c-tiles
        short8 vf0 = *(const short8*)(vbase + m0);
        short8 vf1 = *(const short8*)(vbase + 16 * (size_t)HW + m0);
        short8 vf2 = *(const short8*)(vbase + 32 * (size_t)HW + m0);
        short8 vf3 = *(const short8*)(vbase + 48 * (size_t)HW + m0);

        // S'[m][n] tiles: D[i=m-local][j=n-local]
        f32x4 s0 = __builtin_amdgcn_mfma_f32_16x16x32_bf16(kf0, qf, zf, 0, 0, 0);
        f32x4 s1 = __builtin_amdgcn_mfma_f32_16x16x32_bf16(kf1, qf, zf, 0, 0, 0);

        // online softmax over the 32 m of this step (per column n)
        float tmax = fmaxf(fmaxf(fmaxf(s0[0], s0[1]), fmaxf(s0[2], s0[3])),
                           fmaxf(fmaxf(s1[0], s1[1]), fmaxf(s1[2], s1[3])));
        tmax = fmaxf(tmax, __shfl_xor(tmax, 16));
        tmax = fmaxf(tmax, __shfl_xor(tmax, 32));
        float mnew = fmaxf(mrun, tmax);
        float corr = __expf(mrun - mnew);
        float p00 = __expf(s0[0] - mnew), p01 = __expf(s0[1] - mnew);
        float p02 = __expf(s0[2] - mnew), p03 = __expf(s0[3] - mnew);
        float p10 = __expf(s1[0] - mnew), p11 = __expf(s1[1] - mnew);
        float p12 = __expf(s1[2] - mnew), p13 = __expf(s1[3] - mnew);
        float tsum = p00 + p01 + p02 + p03 + p10 + p11 + p12 + p13;
        tsum += __shfl_xor(tsum, 16);
        tsum += __shfl_xor(tsum, 32);
        lrun = lrun * corr + tsum;
        mrun = mnew;
        acc0 *= corr; acc1 *= corr; acc2 *= corr; acc3 *= corr;

        // pack P to bf16 pairs: pk[h][p] = regs (2p, 2p+1) of m-half h
        int pk00, pk01, pk10, pk11;
        asm("v_cvt_pk_bf16_f32 %0, %1, %2" : "=v"(pk00) : "v"(p00), "v"(p01));
        asm("v_cvt_pk_bf16_f32 %0, %1, %2" : "=v"(pk01) : "v"(p02), "v"(p03));
        asm("v_cvt_pk_bf16_f32 %0, %1, %2" : "=v"(pk10) : "v"(p10), "v"(p11));
        asm("v_cvt_pk_bf16_f32 %0, %1, %2" : "=v"(pk11) : "v"(p12), "v"(p13));

        // transpose to B-frag: dword d <- pk[g>>1][d&1] from lane (2(g&1)+(d>>1))*16+col
        int d0a = __builtin_amdgcn_ds_bpermute(addrA, pk00);
        int d0b = __builtin_amdgcn_ds_bpermute(addrA, pk10);
        int d1a = __builtin_amdgcn_ds_bpermute(addrA, pk01);
        int d1b = __builtin_amdgcn_ds_bpermute(addrA, pk11);
        int d2a = __builtin_amdgcn_ds_bpermute(addrB, pk00);
        int d2b = __builtin_amdgcn_ds_bpermute(addrB, pk10);
        int d3a = __builtin_amdgcn_ds_bpermute(addrB, pk01);
        int d3b = __builtin_amdgcn_ds_bpermute(addrB, pk11);
        union { int i[4]; short8 s; } bp;
        bp.i[0] = hsel ? d0b : d0a;
        bp.i[1] = hsel ? d1b : d1a;
        bp.i[2] = hsel ? d2b : d2a;
        bp.i[3] = hsel ? d3b : d3a;

        acc0 = __builtin_amdgcn_mfma_f32_16x16x32_bf16(vf0, bp.s, acc0, 0, 0, 0);
        acc1 = __builtin_amdgcn_mfma_f32_16x16x32_bf16(vf1, bp.s, acc1, 0, 0, 0);
        acc2 = __builtin_amdgcn_mfma_f32_16x16x32_bf16(vf2, bp.s, acc2, 0, 0, 0);
        acc3 = __builtin_amdgcn_mfma_f32_16x16x32_bf16(vf3, bp.s, acc3, 0, 0, 0);
    }

    float gma = gammap[0];
    float linv = 1.f / lrun;
    #pragma unroll
    for (int ci = 0; ci < 4; ++ci) {
        const f32x4 a = ci == 0 ? acc0 : ci == 1 ? acc1 : ci == 2 ? acc2 : acc3;
        #pragma unroll
        for (int r = 0; r < 4; ++r) {
            int c = ci * 16 + (g << 2) + r;
            size_t idx = ((size_t)(b * C + c) << 12) + n0 + colL;
            out[idx] = gma * a[r] * linv + es[idx];
        }
    }
}

// ---------------- refine conv1x1 over concat [cross, es] ----------------
__global__ void refine_kernel(const float* __restrict__ cross, const float* __restrict__ es,
                              const float* __restrict__ rw, const float* __restrict__ rb,
                              float* __restrict__ y) {
    int idx = blockIdx.x * 256 + threadIdx.x;  // NB*TWOC*HW
    int hw = idx & 4095;
    int t  = idx >> 12;
    int o  = t & 127;
    int b  = t >> 7;
    const float* c1 = cross + (size_t)(b * C) * HW + hw;
    const float* c2 = es    + (size_t)(b * C) * HW + hw;
    const float* w  = rw + o * TWOC;
    float acc = rb[o];
    for (int c = 0; c < C; ++c) acc += c1[(size_t)c * HW] * w[c];
    for (int c = 0; c < C; ++c) acc += c2[(size_t)c * HW] * w[C + c];
    y[idx] = acc;
}

// ---------------- BN stats per channel ----------------
__global__ void bn_stats_kernel(const float* __restrict__ y,
                                float* __restrict__ meanv, float* __restrict__ varv) {
    int o = blockIdx.x, tid = threadIdx.x;
    float s = 0.f, s2 = 0.f;
    for (int i = tid; i < NB * HW; i += 256) {
        int b = i >> 12, hw = i & 4095;
        float val = y[(size_t)(b * TWOC + o) * HW + hw];
        s += val; s2 += val * val;
    }
    for (int d = 32; d > 0; d >>= 1) { s += __shfl_down(s, d); s2 += __shfl_down(s2, d); }
    __shared__ float rs[4], rs2[4];
    if ((tid & 63) == 0) { rs[tid >> 6] = s; rs2[tid >> 6] = s2; }
    __syncthreads();
    if (tid == 0) {
        float S = rs[0] + rs[1] + rs[2] + rs[3];
        float S2 = rs2[0] + rs2[1] + rs2[2] + rs2[3];
        float m = S * (1.f / (NB * HW));
        meanv[o] = m;
        varv[o]  = S2 * (1.f / (NB * HW)) - m * m;
    }
}

// ---------------- BN apply + relu (in place on d_out) ----------------
__global__ void bn_apply_kernel(float* __restrict__ y, const float* __restrict__ meanv,
                                const float* __restrict__ varv, const float* __restrict__ sc,
                                const float* __restrict__ bi) {
    int idx = blockIdx.x * 256 + threadIdx.x;  // NB*TWOC*HW
    int o = (idx >> 12) & 127;
    float xn = (y[idx] - meanv[o]) * rsqrtf(varv[o] + 1e-5f);
    y[idx] = fmaxf(xn * sc[o] + bi[o], 0.f);
}

extern "C" void kernel_launch(void* const* d_in, const int* in_sizes, int n_in,
                              void* d_out, int out_size, void* d_ws, size_t ws_size,
                              hipStream_t stream) {
    const float* swin   = (const float*)d_in[0];
    const float* resnet = (const float*)d_in[1];
    const float* proj_w = (const float*)d_in[2];
    const float* proj_b = (const float*)d_in[3];
    const float* ca_w1  = (const float*)d_in[4];
    const float* ca_w2  = (const float*)d_in[5];
    const float* sa_w   = (const float*)d_in[6];
    const float* sa_b   = (const float*)d_in[7];
    const float* q_w    = (const float*)d_in[8];
    const float* q_b    = (const float*)d_in[9];
    const float* k_w    = (const float*)d_in[10];
    const float* k_b    = (const float*)d_in[11];
    const float* v_w    = (const float*)d_in[12];
    const float* v_b    = (const float*)d_in[13];
    const float* gamma  = (const float*)d_in[14];
    const float* ref_w  = (const float*)d_in[15];
    const float* ref_b  = (const float*)d_in[16];
    const float* bn_sc  = (const float*)d_in[17];
    const float* bn_bi  = (const float*)d_in[18];
    float* out = (float*)d_out;

    float* ws = (float*)d_ws;
    float* s      = ws;                 // 1048576
    float* r      = s + 1048576;        // 1048576
    float* cross  = r + 1048576;        // 1048576
    float* avg_s  = cross + 1048576;    // 256
    float* avg_r  = avg_s + 256;        // 256
    float* ca_s   = avg_r + 256;        // 256
    float* ca_r   = ca_s + 256;         // 256
    float* avgc_s = ca_r + 256;         // 16384
    float* maxc_s = avgc_s + 16384;     // 16384
    float* avgc_r = maxc_s + 16384;     // 16384
    float* maxc_r = avgc_r + 16384;     // 16384
    float* sa_s   = maxc_r + 16384;     // 16384
    float* sa_r   = sa_s + 16384;       // 16384
    float* bn_m   = sa_r + 16384;       // 128
    float* bn_v   = bn_m + 128;         // 128
    ushort* q_t   = (ushort*)(bn_v + 128);  // 131072 ushorts
    ushort* k_t   = q_t + 131072;           // 131072
    ushort* v_t   = k_t + 131072;           // 1048576

    // 1. projections
    conv1x1_kernel<<<NB * C * HW / 256, 256, 0, stream>>>(swin, proj_w, proj_b, s, CIN, C);
    conv1x1_kernel<<<NB * C * HW / 256, 256, 0, stream>>>(resnet, proj_w, proj_b, r, CIN, C);
    // 2. channel attention
    mean_hw_kernel<<<NB * C, 256, 0, stream>>>(s, avg_s);
    mean_hw_kernel<<<NB * C, 256, 0, stream>>>(r, avg_r);
    ca_kernel<<<1, 256, 0, stream>>>(avg_s, ca_w1, ca_w2, ca_s);
    ca_kernel<<<1, 256, 0, stream>>>(avg_r, ca_w1, ca_w2, ca_r);
    // 3. spatial attention
    chan_pool_kernel<<<NB * HW / 256, 256, 0, stream>>>(s, avgc_s, maxc_s);
    chan_pool_kernel<<<NB * HW / 256, 256, 0, stream>>>(r, avgc_r, maxc_r);
    sa_conv_kernel<<<NB * HW / 256, 256, 0, stream>>>(avgc_s, maxc_s, sa_w, sa_b, sa_s);
    sa_conv_kernel<<<NB * HW / 256, 256, 0, stream>>>(avgc_r, maxc_r, sa_w, sa_b, sa_r);
    // 4. apply gates (s -> es, r -> er, in place)
    apply_attn_kernel<<<NB * C * HW / 256, 256, 0, stream>>>(s, ca_s, sa_s);
    apply_attn_kernel<<<NB * C * HW / 256, 256, 0, stream>>>(r, ca_r, sa_r);
    // 5. q, k, v projections -> bf16 MFMA layouts
    qk_proj_kernel<<<NB * HW / 256, 256, 0, stream>>>(s, r, q_w, q_b, k_w, k_b, q_t, k_t);
    v_proj_kernel<<<NB * C * HW / 256, 256, 0, stream>>>(r, v_w, v_b, v_t);
    // 6. MFMA flash cross-attention: cross = gamma*attn_out + es
    cross_attn_mfma<<<256, 256, 0, stream>>>(q_t, k_t, v_t, s, gamma, cross);
    // 7. refine over concat [cross, es] -> d_out
    refine_kernel<<<NB * TWOC * HW / 256, 256, 0, stream>>>(cross, s, ref_w, ref_b, out);
    // 8. BN stats + apply + relu
    bn_stats_kernel<<<TWOC, 256, 0, stream>>>(out, bn_m, bn_v);
    bn_apply_kernel<<<NB * TWOC * HW / 256, 256, 0, stream>>>(out, bn_m, bn_v, bn_sc, bn_bi);
}

// Round 3
// 213.589 us; speedup vs baseline: 2.9833x; 1.9283x over previous
//
#include <hip/hip_runtime.h>
#include <hip/hip_bf16.h>
#include <math.h>

#define NB   4      // batch
#define CIN  128
#define C    64
#define HH   64
#define WW   64
#define HW   4096
#define C8   8
#define RR   4
#define TWOC 128

typedef __attribute__((ext_vector_type(8))) short short8;
typedef __attribute__((ext_vector_type(4))) float f32x4;
typedef __attribute__((ext_vector_type(4))) int int4v;

__device__ inline ushort f2bf(float f) {
    union { float f; unsigned u; } x{ f };
    unsigned r = x.u + 0x7FFFu + ((x.u >> 16) & 1u);   // RNE
    return (ushort)(r >> 16);
}

// ---------------- proj conv1x1 for both images, register-tiled ----------------
// y[b][o][hw] = bias[o] + sum_c x[b][c][hw] * w[o][c]
// thread: 4 hw (float4) x 8 output channels. grid = 2 img * 4 b * 4 hwT * 8 oT = 256
__global__ __launch_bounds__(256) void proj_conv_kernel(
    const float* __restrict__ sw, const float* __restrict__ rn,
    const float* __restrict__ w, const float* __restrict__ bias,
    float* __restrict__ s, float* __restrict__ r) {
    int bid = blockIdx.x;
    int oT  = bid & 7;
    int hwT = (bid >> 3) & 3;
    int b   = (bid >> 5) & 3;
    int img = bid >> 7;
    const float* x = (img ? rn : sw) + (size_t)b * CIN * HW;
    float* y = (img ? r : s) + (size_t)b * C * HW;
    int hw0 = (hwT << 10) + (threadIdx.x << 2);
    int o0  = oT << 3;
    f32x4 acc[8];
    #pragma unroll
    for (int oi = 0; oi < 8; ++oi) acc[oi] = f32x4(bias[o0 + oi]);
    const float* xp = x + hw0;
    #pragma unroll 4
    for (int c = 0; c < CIN; ++c) {
        f32x4 xv = *(const f32x4*)(xp + (size_t)c * HW);
        #pragma unroll
        for (int oi = 0; oi < 8; ++oi) acc[oi] += xv * w[(o0 + oi) * CIN + c];
    }
    #pragma unroll
    for (int oi = 0; oi < 8; ++oi)
        *(f32x4*)(y + (size_t)(o0 + oi) * HW + hw0) = acc[oi];
}

// ---------------- mean over HW per (b,c) ----------------
__global__ void mean_hw_kernel(const float* __restrict__ x, float* __restrict__ out) {
    int bc = blockIdx.x, tid = threadIdx.x;
    float s = 0.f;
    for (int i = tid; i < HW; i += 256) s += x[(size_t)bc * HW + i];
    for (int d = 32; d > 0; d >>= 1) s += __shfl_down(s, d);
    __shared__ float rs[4];
    if ((tid & 63) == 0) rs[tid >> 6] = s;
    __syncthreads();
    if (tid == 0) out[bc] = (rs[0] + rs[1] + rs[2] + rs[3]) * (1.f / HW);
}

// ---------------- channel attention MLP ----------------
__global__ void ca_kernel(const float* __restrict__ avg, const float* __restrict__ w1,
                          const float* __restrict__ w2, float* __restrict__ out) {
    int tid = threadIdx.x;           // 256 = NB*C
    int b = tid >> 6, c = tid & 63;
    __shared__ float h[NB][RR];
    if (tid < NB * RR) {
        int hb = tid >> 2, hr = tid & 3;
        float a = 0.f;
        for (int cc = 0; cc < C; ++cc) a += avg[hb * C + cc] * w1[hr * C + cc];
        h[hb][hr] = fmaxf(a, 0.f);
    }
    __syncthreads();
    float a = 0.f;
    for (int r = 0; r < RR; ++r) a += h[b][r] * w2[c * RR + r];
    out[b * C + c] = 1.f / (1.f + __expf(-a));
}

// ---------------- channel avg/max pooling ----------------
__global__ void chan_pool_kernel(const float* __restrict__ x,
                                 float* __restrict__ avgo, float* __restrict__ maxo) {
    int idx = blockIdx.x * 256 + threadIdx.x;  // NB*HW
    int b = idx >> 12, hw = idx & 4095;
    const float* xp = x + (size_t)(b * C) * HW + hw;
    float s = 0.f, m = -1e30f;
    for (int c = 0; c < C; ++c) { float v = xp[(size_t)c * HW]; s += v; m = fmaxf(m, v); }
    avgo[idx] = s * (1.f / C);
    maxo[idx] = m;
}

// ---------------- spatial attention 7x7 conv + sigmoid ----------------
__global__ void sa_conv_kernel(const float* __restrict__ avgc, const float* __restrict__ maxc,
                               const float* __restrict__ w, const float* __restrict__ bsa,
                               float* __restrict__ out) {
    __shared__ float wsh[98];
    if (threadIdx.x < 98) wsh[threadIdx.x] = w[threadIdx.x];
    __syncthreads();
    int idx = blockIdx.x * 256 + threadIdx.x;  // NB*HW
    int b = idx >> 12, hw = idx & 4095;
    int y0 = hw >> 6, x0 = hw & 63;
    float acc = bsa[0];
    for (int dy = -3; dy <= 3; ++dy) {
        int yy = y0 + dy; if (yy < 0 || yy >= HH) continue;
        for (int dx = -3; dx <= 3; ++dx) {
            int xx = x0 + dx; if (xx < 0 || xx >= WW) continue;
            int widx = (dy + 3) * 7 + (dx + 3);
            int p = b * HW + yy * WW + xx;
            acc += avgc[p] * wsh[widx] + maxc[p] * wsh[49 + widx];
        }
    }
    out[idx] = 1.f / (1.f + __expf(-acc));
}

// ---------------- apply channel & spatial gates in place ----------------
__global__ void apply_attn_kernel(float* __restrict__ x, const float* __restrict__ ca,
                                  const float* __restrict__ sa) {
    int idx = blockIdx.x * 256 + threadIdx.x;  // NB*C*HW
    int hw = idx & 4095;
    int bc = idx >> 12;
    int b  = bc >> 6;
    x[idx] = x[idx] * ca[bc] * sa[b * HW + hw];
}

// ---------------- fused v + qk projections -> bf16 MFMA layouts ----------------
// blocks [0,128): v: thread = 4 hw x 8 out-ch; v_t[b][c][hw] bf16
// blocks [128,144): qk: thread = 4 hw x (8 q + 8 k); q_t/k_t [b][hw][8] bf16
__global__ __launch_bounds__(256) void vqk_proj_kernel(
    const float* __restrict__ es, const float* __restrict__ er,
    const float* __restrict__ vw, const float* __restrict__ vbv,
    const float* __restrict__ qw, const float* __restrict__ qbv,
    const float* __restrict__ kw, const float* __restrict__ kbv,
    ushort* __restrict__ v_t, ushort* __restrict__ q_t, ushort* __restrict__ k_t) {
    int bid = blockIdx.x;
    if (bid < 128) {
        int oT  = bid & 7;
        int hwT = (bid >> 3) & 3;
        int b   = bid >> 5;
        int hw0 = (hwT << 10) + (threadIdx.x << 2);
        int o0  = oT << 3;
        const float* xp = er + (size_t)b * C * HW + hw0;
        f32x4 acc[8];
        #pragma unroll
        for (int oi = 0; oi < 8; ++oi) acc[oi] = f32x4(vbv[o0 + oi]);
        #pragma unroll 4
        for (int c = 0; c < C; ++c) {
            f32x4 xv = *(const f32x4*)(xp + (size_t)c * HW);
            #pragma unroll
            for (int oi = 0; oi < 8; ++oi) acc[oi] += xv * vw[(o0 + oi) * C + c];
        }
        #pragma unroll
        for (int oi = 0; oi < 8; ++oi) {
            union { ushort u[4]; uint2 v; } o;
            #pragma unroll
            for (int j = 0; j < 4; ++j) o.u[j] = f2bf(acc[oi][j]);
            *(uint2*)(v_t + (size_t)(b * C + o0 + oi) * HW + hw0) = o.v;
        }
    } else {
        int t   = bid - 128;
        int hwT = t & 3;
        int b   = t >> 2;
        int hw0 = (hwT << 10) + (threadIdx.x << 2);
        const float* esp = es + (size_t)b * C * HW + hw0;
        const float* erp = er + (size_t)b * C * HW + hw0;
        f32x4 qa[8], ka[8];
        #pragma unroll
        for (int o = 0; o < 8; ++o) { qa[o] = f32x4(qbv[o]); ka[o] = f32x4(kbv[o]); }
        #pragma unroll 2
        for (int c = 0; c < C; ++c) {
            f32x4 xs = *(const f32x4*)(esp + (size_t)c * HW);
            f32x4 xr = *(const f32x4*)(erp + (size_t)c * HW);
            #pragma unroll
            for (int o = 0; o < 8; ++o) { qa[o] += xs * qw[o * C + c]; ka[o] += xr * kw[o * C + c]; }
        }
        #pragma unroll
        for (int j = 0; j < 4; ++j) {
            union { ushort u[8]; int4v v; } qo, ko;
            #pragma unroll
            for (int o = 0; o < 8; ++o) { qo.u[o] = f2bf(qa[o][j]); ko.u[o] = f2bf(ka[o][j]); }
            size_t hw = hw0 + j;
            *(int4v*)(q_t + ((size_t)b * HW + hw) * 8) = qo.v;
            *(int4v*)(k_t + ((size_t)b * HW + hw) * 8) = ko.v;
        }
    }
}

// ---------------- MFMA flash cross-attention, 4-way m-split ----------------
// Block = (b, n0): 4 waves each handle 1024 of 4096 m, merge via LDS flash-combine.
__global__ __launch_bounds__(256) void cross_attn_mfma(
    const ushort* __restrict__ q_t, const ushort* __restrict__ k_t,
    const ushort* __restrict__ v_t, const float* __restrict__ es,
    const float* __restrict__ gammap, float* __restrict__ out)
{
    const int tid  = threadIdx.x;
    const int lane = tid & 63;
    const int ws   = tid >> 6;                 // m-split index 0..3
    const int b    = blockIdx.x >> 8;          // 256 n-tiles per batch
    const int n0   = (blockIdx.x & 255) << 4;
    const int g    = lane >> 4;
    const int colL = lane & 15;
    const int hsel = g >> 1;
    const int addrA = (((g & 1) << 5) + colL) << 2;    // src lane*4 for b-frag dw 0,1
    const int addrB = addrA + 64;                      // +16 lanes for dw 2,3

    // Q b-frag: lanes<16 hold Q[c8=0..7][n0+lane]; zero-pad k>=8
    short8 qf = short8(0);
    if (lane < 16) qf = *(const short8*)(q_t + ((size_t)(b * HW) + n0 + lane) * 8);

    f32x4 acc0 = {0.f,0.f,0.f,0.f}, acc1 = acc0, acc2 = acc0, acc3 = acc0;
    const f32x4 zf = {0.f,0.f,0.f,0.f};
    float mrun = -1e30f, lrun = 0.f;

    const ushort* kbase = k_t + (size_t)(b * HW) * 8;
    const ushort* vbase = v_t + (size_t)(b * C) * HW + colL * (size_t)HW + (g << 3);

    const int mbeg = ws << 10, mend = mbeg + 1024;
    for (int m0 = mbeg; m0 < mend; m0 += 32) {
        short8 kf0 = short8(0), kf1 = short8(0);
        if (lane < 16) {
            kf0 = *(const short8*)(kbase + ((size_t)(m0 + lane)) * 8);
            kf1 = *(const short8*)(kbase + ((size_t)(m0 + 16 + lane)) * 8);
        }
        short8 vf0 = *(const short8*)(vbase + m0);
        short8 vf1 = *(const short8*)(vbase + 16 * (size_t)HW + m0);
        short8 vf2 = *(const short8*)(vbase + 32 * (size_t)HW + m0);
        short8 vf3 = *(const short8*)(vbase + 48 * (size_t)HW + m0);

        f32x4 s0 = __builtin_amdgcn_mfma_f32_16x16x32_bf16(kf0, qf, zf, 0, 0, 0);
        f32x4 s1 = __builtin_amdgcn_mfma_f32_16x16x32_bf16(kf1, qf, zf, 0, 0, 0);

        float tmax = fmaxf(fmaxf(fmaxf(s0[0], s0[1]), fmaxf(s0[2], s0[3])),
                           fmaxf(fmaxf(s1[0], s1[1]), fmaxf(s1[2], s1[3])));
        tmax = fmaxf(tmax, __shfl_xor(tmax, 16));
        tmax = fmaxf(tmax, __shfl_xor(tmax, 32));
        float mnew = fmaxf(mrun, tmax);
        float corr = __expf(mrun - mnew);
        float p00 = __expf(s0[0] - mnew), p01 = __expf(s0[1] - mnew);
        float p02 = __expf(s0[2] - mnew), p03 = __expf(s0[3] - mnew);
        float p10 = __expf(s1[0] - mnew), p11 = __expf(s1[1] - mnew);
        float p12 = __expf(s1[2] - mnew), p13 = __expf(s1[3] - mnew);
        float tsum = p00 + p01 + p02 + p03 + p10 + p11 + p12 + p13;
        tsum += __shfl_xor(tsum, 16);
        tsum += __shfl_xor(tsum, 32);
        lrun = lrun * corr + tsum;
        mrun = mnew;
        acc0 *= corr; acc1 *= corr; acc2 *= corr; acc3 *= corr;

        int pk00, pk01, pk10, pk11;
        asm("v_cvt_pk_bf16_f32 %0, %1, %2" : "=v"(pk00) : "v"(p00), "v"(p01));
        asm("v_cvt_pk_bf16_f32 %0, %1, %2" : "=v"(pk01) : "v"(p02), "v"(p03));
        asm("v_cvt_pk_bf16_f32 %0, %1, %2" : "=v"(pk10) : "v"(p10), "v"(p11));
        asm("v_cvt_pk_bf16_f32 %0, %1, %2" : "=v"(pk11) : "v"(p12), "v"(p13));

        int d0a = __builtin_amdgcn_ds_bpermute(addrA, pk00);
        int d0b = __builtin_amdgcn_ds_bpermute(addrA, pk10);
        int d1a = __builtin_amdgcn_ds_bpermute(addrA, pk01);
        int d1b = __builtin_amdgcn_ds_bpermute(addrA, pk11);
        int d2a = __builtin_amdgcn_ds_bpermute(addrB, pk00);
        int d2b = __builtin_amdgcn_ds_bpermute(addrB, pk10);
        int d3a = __builtin_amdgcn_ds_bpermute(addrB, pk01);
        int d3b = __builtin_amdgcn_ds_bpermute(addrB, pk11);
        union { int i[4]; short8 s; } bp;
        bp.i[0] = hsel ? d0b : d0a;
        bp.i[1] = hsel ? d1b : d1a;
        bp.i[2] = hsel ? d2b : d2a;
        bp.i[3] = hsel ? d3b : d3a;

        acc0 = __builtin_amdgcn_mfma_f32_16x16x32_bf16(vf0, bp.s, acc0, 0, 0, 0);
        acc1 = __builtin_amdgcn_mfma_f32_16x16x32_bf16(vf1, bp.s, acc1, 0, 0, 0);
        acc2 = __builtin_amdgcn_mfma_f32_16x16x32_bf16(vf2, bp.s, acc2, 0, 0, 0);
        acc3 = __builtin_amdgcn_mfma_f32_16x16x32_bf16(vf3, bp.s, acc3, 0, 0, 0);
    }

    // ---- flash-combine the 4 m-splits through LDS ----
    __shared__ float paccs[4][64][17];
    __shared__ float pml[4][2][16];
    #pragma unroll
    for (int ci = 0; ci < 4; ++ci) {
        const f32x4 a = ci == 0 ? acc0 : ci == 1 ? acc1 : ci == 2 ? acc2 : acc3;
        #pragma unroll
        for (int r = 0; r < 4; ++r)
            paccs[ws][ci * 16 + (g << 2) + r][colL] = a[r];
    }
    if (lane < 16) { pml[ws][0][lane] = mrun; pml[ws][1][lane] = lrun; }
    __syncthreads();

    float m0v = pml[0][0][colL], m1v = pml[1][0][colL];
    float m2v = pml[2][0][colL], m3v = pml[3][0][colL];
    float M = fmaxf(fmaxf(m0v, m1v), fmaxf(m2v, m3v));
    float e0 = __expf(m0v - M), e1 = __expf(m1v - M);
    float e2 = __expf(m2v - M), e3 = __expf(m3v - M);
    float L = pml[0][1][colL] * e0 + pml[1][1][colL] * e1
            + pml[2][1][colL] * e2 + pml[3][1][colL] * e3;
    float scale = gammap[0] / L;
    #pragma unroll
    for (int r = 0; r < 4; ++r) {
        int c = (ws << 4) + (g << 2) + r;
        float o = paccs[0][c][colL] * e0 + paccs[1][c][colL] * e1
                + paccs[2][c][colL] * e2 + paccs[3][c][colL] * e3;
        size_t idx = ((size_t)(b * C + c) << 12) + n0 + colL;
        out[idx] = scale * o + es[idx];
    }
}

// ---------------- refine conv1x1 over concat [cross, es], register-tiled ----------------
// grid = 4 b * 4 hwT * 16 oT = 256 blocks
__global__ __launch_bounds__(256) void refine_conv_kernel(
    const float* __restrict__ cross, const float* __restrict__ es,
    const float* __restrict__ rw, const float* __restrict__ rb,
    float* __restrict__ y) {
    int bid = blockIdx.x;
    int oT  = bid & 15;
    int hwT = (bid >> 4) & 3;
    int b   = bid >> 6;
    int hw0 = (hwT << 10) + (threadIdx.x << 2);
    int o0  = oT << 3;
    const float* c1 = cross + (size_t)b * C * HW + hw0;
    const float* c2 = es    + (size_t)b * C * HW + hw0;
    f32x4 acc[8];
    #pragma unroll
    for (int oi = 0; oi < 8; ++oi) acc[oi] = f32x4(rb[o0 + oi]);
    #pragma unroll 4
    for (int c = 0; c < C; ++c) {
        f32x4 xv = *(const f32x4*)(c1 + (size_t)c * HW);
        #pragma unroll
        for (int oi = 0; oi < 8; ++oi) acc[oi] += xv * rw[(o0 + oi) * TWOC + c];
    }
    #pragma unroll 4
    for (int c = 0; c < C; ++c) {
        f32x4 xv = *(const f32x4*)(c2 + (size_t)c * HW);
        #pragma unroll
        for (int oi = 0; oi < 8; ++oi) acc[oi] += xv * rw[(o0 + oi) * TWOC + C + c];
    }
    #pragma unroll
    for (int oi = 0; oi < 8; ++oi)
        *(f32x4*)(y + (size_t)(b * TWOC + o0 + oi) * HW + hw0) = acc[oi];
}

// ---------------- BN stats per channel ----------------
__global__ void bn_stats_kernel(const float* __restrict__ y,
                                float* __restrict__ meanv, float* __restrict__ varv) {
    int o = blockIdx.x, tid = threadIdx.x;
    float s = 0.f, s2 = 0.f;
    for (int i = tid; i < NB * HW; i += 256) {
        int b = i >> 12, hw = i & 4095;
        float val = y[(size_t)(b * TWOC + o) * HW + hw];
        s += val; s2 += val * val;
    }
    for (int d = 32; d > 0; d >>= 1) { s += __shfl_down(s, d); s2 += __shfl_down(s2, d); }
    __shared__ float rs[4], rs2[4];
    if ((tid & 63) == 0) { rs[tid >> 6] = s; rs2[tid >> 6] = s2; }
    __syncthreads();
    if (tid == 0) {
        float S = rs[0] + rs[1] + rs[2] + rs[3];
        float S2 = rs2[0] + rs2[1] + rs2[2] + rs2[3];
        float m = S * (1.f / (NB * HW));
        meanv[o] = m;
        varv[o]  = S2 * (1.f / (NB * HW)) - m * m;
    }
}

// ---------------- BN apply + relu (in place on d_out) ----------------
__global__ void bn_apply_kernel(float* __restrict__ y, const float* __restrict__ meanv,
                                const float* __restrict__ varv, const float* __restrict__ sc,
                                const float* __restrict__ bi) {
    int idx = blockIdx.x * 256 + threadIdx.x;  // NB*TWOC*HW
    int o = (idx >> 12) & 127;
    float xn = (y[idx] - meanv[o]) * rsqrtf(varv[o] + 1e-5f);
    y[idx] = fmaxf(xn * sc[o] + bi[o], 0.f);
}

extern "C" void kernel_launch(void* const* d_in, const int* in_sizes, int n_in,
                              void* d_out, int out_size, void* d_ws, size_t ws_size,
                              hipStream_t stream) {
    const float* swin   = (const float*)d_in[0];
    const float* resnet = (const float*)d_in[1];
    const float* proj_w = (const float*)d_in[2];
    const float* proj_b = (const float*)d_in[3];
    const float* ca_w1  = (const float*)d_in[4];
    const float* ca_w2  = (const float*)d_in[5];
    const float* sa_w   = (const float*)d_in[6];
    const float* sa_b   = (const float*)d_in[7];
    const float* q_w    = (const float*)d_in[8];
    const float* q_b    = (const float*)d_in[9];
    const float* k_w    = (const float*)d_in[10];
    const float* k_b    = (const float*)d_in[11];
    const float* v_w    = (const float*)d_in[12];
    const float* v_b    = (const float*)d_in[13];
    const float* gamma  = (const float*)d_in[14];
    const float* ref_w  = (const float*)d_in[15];
    const float* ref_b  = (const float*)d_in[16];
    const float* bn_sc  = (const float*)d_in[17];
    const float* bn_bi  = (const float*)d_in[18];
    float* out = (float*)d_out;

    float* ws = (float*)d_ws;
    float* s      = ws;                 // 1048576
    float* r      = s + 1048576;        // 1048576
    float* cross  = r + 1048576;        // 1048576
    float* avg_s  = cross + 1048576;    // 256
    float* avg_r  = avg_s + 256;        // 256
    float* ca_s   = avg_r + 256;        // 256
    float* ca_r   = ca_s + 256;         // 256
    float* avgc_s = ca_r + 256;         // 16384
    float* maxc_s = avgc_s + 16384;     // 16384
    float* avgc_r = maxc_s + 16384;     // 16384
    float* maxc_r = avgc_r + 16384;     // 16384
    float* sa_s   = maxc_r + 16384;     // 16384
    float* sa_r   = sa_s + 16384;       // 16384
    float* bn_m   = sa_r + 16384;       // 128
    float* bn_v   = bn_m + 128;         // 128
    ushort* q_t   = (ushort*)(bn_v + 128);  // 131072 ushorts
    ushort* k_t   = q_t + 131072;           // 131072
    ushort* v_t   = k_t + 131072;           // 1048576

    // 1. projections (both images, one launch)
    proj_conv_kernel<<<256, 256, 0, stream>>>(swin, resnet, proj_w, proj_b, s, r);
    // 2. channel attention
    mean_hw_kernel<<<NB * C, 256, 0, stream>>>(s, avg_s);
    mean_hw_kernel<<<NB * C, 256, 0, stream>>>(r, avg_r);
    ca_kernel<<<1, 256, 0, stream>>>(avg_s, ca_w1, ca_w2, ca_s);
    ca_kernel<<<1, 256, 0, stream>>>(avg_r, ca_w1, ca_w2, ca_r);
    // 3. spatial attention
    chan_pool_kernel<<<NB * HW / 256, 256, 0, stream>>>(s, avgc_s, maxc_s);
    chan_pool_kernel<<<NB * HW / 256, 256, 0, stream>>>(r, avgc_r, maxc_r);
    sa_conv_kernel<<<NB * HW / 256, 256, 0, stream>>>(avgc_s, maxc_s, sa_w, sa_b, sa_s);
    sa_conv_kernel<<<NB * HW / 256, 256, 0, stream>>>(avgc_r, maxc_r, sa_w, sa_b, sa_r);
    // 4. apply gates (s -> es, r -> er, in place)
    apply_attn_kernel<<<NB * C * HW / 256, 256, 0, stream>>>(s, ca_s, sa_s);
    apply_attn_kernel<<<NB * C * HW / 256, 256, 0, stream>>>(r, ca_r, sa_r);
    // 5. v + q/k projections -> bf16 MFMA layouts (one launch)
    vqk_proj_kernel<<<144, 256, 0, stream>>>(s, r, v_w, v_b, q_w, q_b, k_w, k_b, v_t, q_t, k_t);
    // 6. MFMA flash cross-attention (4-way m-split): cross = gamma*attn_out + es
    cross_attn_mfma<<<NB * 256, 256, 0, stream>>>(q_t, k_t, v_t, s, gamma, cross);
    // 7. refine over concat [cross, es] -> d_out
    refine_conv_kernel<<<256, 256, 0, stream>>>(cross, s, ref_w, ref_b, out);
    // 8. BN stats + apply + relu
    bn_stats_kernel<<<TWOC, 256, 0, stream>>>(out, bn_m, bn_v);
    bn_apply_kernel<<<NB * TWOC * HW / 256, 256, 0, stream>>>(out, bn_m, bn_v, bn_sc, bn_bi);
}